// Round 5
// baseline (2069.685 us; speedup 1.0000x reference)
//
#include <hip/hip_runtime.h>

#define N_PTS  16384
#define B_SZ   8
#define NGROUP 1024
#define KNN_K  32
#define ATTR   7

// d_out layout (floats), reference return order:
// neighborhood (8,1024,32,7), center_idx (8,1024), centroids_attrs (8,1024,7), centroids_coors (8,1024,3)
#define OFF_NB     0
#define OFF_IDX    (B_SZ * NGROUP * KNN_K * ATTR)            // 1835008
#define OFF_CATTR  (OFF_IDX + B_SZ * NGROUP)                 // 1843200
#define OFF_CCOORD (OFF_CATTR + B_SZ * NGROUP * ATTR)        // 1900544

typedef float v2f __attribute__((ext_vector_type(2)));                 // packed-f32 math
typedef float f2u __attribute__((ext_vector_type(2), aligned(4)));     // 4B-aligned vec load

// ---------------------------------------------------------------------------
// DPP 64-lane reductions (VALU-only; no DS-pipe traffic).
// ---------------------------------------------------------------------------
template <int CTRL>
__device__ __forceinline__ float fmax_dpp_step(float x) {
    int d = __builtin_amdgcn_update_dpp(__float_as_int(x), __float_as_int(x),
                                        CTRL, 0xf, 0xf, false);
    return fmaxf(x, __int_as_float(d));
}
template <int CTRL>
__device__ __forceinline__ unsigned umin_dpp_step(unsigned x) {
    unsigned d = (unsigned)__builtin_amdgcn_update_dpp((int)x, (int)x,
                                                       CTRL, 0xf, 0xf, false);
    return x < d ? x : d;
}

__device__ __forceinline__ float wave_max_f32(float x) {
    x = fmax_dpp_step<0x111>(x);   // row_shr:1
    x = fmax_dpp_step<0x112>(x);   // row_shr:2
    x = fmax_dpp_step<0x114>(x);   // row_shr:4
    x = fmax_dpp_step<0x118>(x);   // row_shr:8
    x = fmax_dpp_step<0x142>(x);   // row_bcast15
    x = fmax_dpp_step<0x143>(x);   // row_bcast31 -> lane63 = full-wave max
    return __int_as_float(__builtin_amdgcn_readlane(__float_as_int(x), 63));
}
__device__ __forceinline__ unsigned wave_min_u32(unsigned x) {
    x = umin_dpp_step<0x111>(x);
    x = umin_dpp_step<0x112>(x);
    x = umin_dpp_step<0x114>(x);
    x = umin_dpp_step<0x118>(x);
    x = umin_dpp_step<0x142>(x);
    x = umin_dpp_step<0x143>(x);
    return (unsigned)__builtin_amdgcn_readlane((int)x, 63);
}

// ---------------------------------------------------------------------------
// Kernel 0: prep — x2[b][n] = sum_a xyz[b][n][a]^2 (sequential, no FMA) and
// SoA transpose xt[b][a][n] for coalesced KNN reads.
// ---------------------------------------------------------------------------
__global__ void prep_kernel(const float* __restrict__ xyz, float* __restrict__ x2,
                            float* __restrict__ xt) {
#pragma clang fp contract(off)
    int i = blockIdx.x * blockDim.x + threadIdx.x;
    if (i >= B_SZ * N_PTS) return;
    const int b = i >> 14;
    const int p = i & (N_PTS - 1);
    const float* q = xyz + (size_t)i * ATTR;
    f2u a01 = *(const f2u*)q;
    f2u a23 = *(const f2u*)(q + 2);
    f2u a45 = *(const f2u*)(q + 4);
    float a6 = q[6];
    float s = a01.x * a01.x;
    s = s + a01.y * a01.y;
    s = s + a23.x * a23.x;
    s = s + a23.y * a23.y;
    s = s + a45.x * a45.x;
    s = s + a45.y * a45.y;
    s = s + a6 * a6;
    x2[i] = s;
    float* T = xt + (size_t)b * ATTR * N_PTS + p;
    T[0 * N_PTS] = a01.x;
    T[1 * N_PTS] = a01.y;
    T[2 * N_PTS] = a23.x;
    T[3 * N_PTS] = a23.y;
    T[4 * N_PTS] = a45.x;
    T[5 * N_PTS] = a45.y;
    T[6 * N_PTS] = a6;
}

// ---------------------------------------------------------------------------
// Kernel 1: farthest point sampling. One 512-thread block per batch.
// Rounds 1-4 lesson (units corrected: FETCH was MB, not GB): RA spills the
// INVARIANT coord registers to scratch and re-reads 192 KB/block/step from
// L2 (~1.45 us/step — the whole cost). Source-level hints never moved its
// occupancy target. So: explicit storage.
//   * x,y planes in LDS as v2f pairs of consecutive points (132 KB static).
//     Per step: 32 conflict-free ds_read_b64/thread = 128 KB/CU @128 B/cyc.
//     132 KB LDS also forces 1 block/CU -> RA budget 256 VGPR naturally.
//   * z + pd in registers (64 VGPRs), pz pinned per-iteration by empty asm
//     ("+v") so it is redefined each step: not remat-able, spill = RMW cost.
//   * pair mapping (2q,2q+1): per-thread scan order strictly ascending ->
//     tie-break (first-max-wins == min index) identical to rounds 1-4.
// Math sequence identical (unfused, sequential; fp contract off).
// ---------------------------------------------------------------------------
#define FOR16(M) M(0) M(1) M(2) M(3) M(4) M(5) M(6) M(7) \
                 M(8) M(9) M(10) M(11) M(12) M(13) M(14) M(15)

#define PZ_DECL(J) v2f pz##J, pd##J;

#define STAGE(J) { \
    const int q = t + (J << 9); \
    const float* r0 = X + (size_t)(q << 1) * ATTR; \
    f2u u0 = *(const f2u*)r0;          float z0 = r0[2]; \
    f2u u1 = *(const f2u*)(r0 + ATTR); float z1 = r0[2 + ATTR]; \
    lx[q] = (v2f){u0.x, u1.x}; \
    ly[q] = (v2f){u0.y, u1.y}; \
    pz##J = (v2f){z0, z1}; \
    pd##J = (v2f){1e10f, 1e10f}; }

#define PT_STEP(J) { \
    const v2f pxv = lx[t + (J << 9)]; \
    const v2f pyv = ly[t + (J << 9)]; \
    v2f dx = pxv - cx2; \
    v2f dy = pyv - cy2; \
    v2f dz = pz##J - cz2; \
    v2f a  = dx * dx; \
    a = a + dy * dy; \
    a = a + dz * dz; \
    v2f nd; \
    nd.x = fminf(pd##J.x, a.x); \
    nd.y = fminf(pd##J.y, a.y); \
    pd##J = nd; \
    if (nd.x > best) { best = nd.x; bidx = (t << 1) + (J << 10); } \
    if (nd.y > best) { best = nd.y; bidx = (t << 1) + (J << 10) + 1; } }

__global__ __launch_bounds__(512)
__attribute__((amdgpu_waves_per_eu(2, 2)))
void fps_kernel(const float* __restrict__ xyz, float* __restrict__ out) {
#pragma clang fp contract(off)
    const int b = blockIdx.x;
    const int t = threadIdx.x;
    const int lane = t & 63;
    const int w = t >> 6;                      // wave 0..7
    const float* X = xyz + (size_t)b * N_PTS * ATTR;

    __shared__ v2f lx[N_PTS / 2];              // {x[2q], x[2q+1]}  (64 KB)
    __shared__ v2f ly[N_PTS / 2];              // {y[2q], y[2q+1]}  (64 KB)
    __shared__ int sel[NGROUP];                // (4 KB)
    __shared__ unsigned long long sbuf[2][8];

    FOR16(PZ_DECL)
    FOR16(STAGE)

    if (t == 0) sel[0] = 0;
    float cx = X[0], cy = X[1], cz = X[2];     // farthest=0 initial centroid
    __syncthreads();

    for (int s = 0; s < NGROUP - 1; ++s) {
        const int par = s & 1;
        // pin pz: redefined each iteration -> cannot be rematerialized, and
        // spilling it would cost a per-step RMW (RA keeps it, like pd).
        asm volatile("" : "+v"(pz0), "+v"(pz1), "+v"(pz2), "+v"(pz3),
                          "+v"(pz4), "+v"(pz5), "+v"(pz6), "+v"(pz7),
                          "+v"(pz8), "+v"(pz9), "+v"(pz10), "+v"(pz11),
                          "+v"(pz12), "+v"(pz13), "+v"(pz14), "+v"(pz15));
        const v2f cx2 = {cx, cx}, cy2 = {cy, cy}, cz2 = {cz, cz};
        float best = -1.0f;
        int   bidx = 0;
        // strict '>' + per-thread ascending scan order == np.argmax semantics.
        FOR16(PT_STEP)
        // wave-level: max distance, then smallest point index among exact ties.
        const float wm = wave_max_f32(best);
        const unsigned cand = (best == wm) ? (unsigned)bidx : 0xFFFFFFFFu;
        const unsigned widx = wave_min_u32(cand);
        if (lane == 0) {
            // d >= 0 so float bits are order-preserving as u32.
            sbuf[par][w] = ((unsigned long long)__float_as_uint(wm) << 32) |
                           (unsigned)(N_PTS - widx);
        }
        __syncthreads();
        // every thread combines the 8 wave keys (uniform broadcast reads).
        unsigned long long bk = sbuf[par][0];
#pragma unroll
        for (int i = 1; i < 8; ++i) {
            const unsigned long long k = sbuf[par][i];
            if (k > bk) bk = k;
        }
        const int win = N_PTS - (int)(unsigned)bk;
        const int sbidx = __builtin_amdgcn_readfirstlane(win);
        if (t == 0) sel[s + 1] = sbidx;
        // uniform (SGPR) address -> scalar load of winner coords, L2-hit.
        const float* q = X + (size_t)sbidx * ATTR;
        cx = q[0]; cy = q[1]; cz = q[2];
    }
    __syncthreads();

    // outputs: center_idx, centroids_attrs, centroids_coors (1024 groups, 512 threads)
    for (int g = t; g < NGROUP; g += 512) {
        const int idx = sel[g];
        const float* q = X + (size_t)idx * ATTR;
        float a0 = q[0], a1 = q[1], a2 = q[2], a3 = q[3], a4 = q[4], a5 = q[5], a6 = q[6];
        out[OFF_IDX + b * NGROUP + g] = (float)idx;
        float* ca = out + OFF_CATTR + (size_t)(b * NGROUP + g) * ATTR;
        ca[0] = a0; ca[1] = a1; ca[2] = a2; ca[3] = a3; ca[4] = a4; ca[5] = a5; ca[6] = a6;
        float* cc = out + OFF_CCOORD + (size_t)(b * NGROUP + g) * 3;
        cc[0] = a0; cc[1] = a1; cc[2] = a2;
    }
}

// ---------------------------------------------------------------------------
// distributed top-32 insert (sorted list lives one-slot-per-lane, lanes 0..31)
// ---------------------------------------------------------------------------
__device__ __forceinline__ void topk_insert(float d2, int p, int lane,
                                            float& ld, int& li, float& kd, int& ki) {
    const bool cand = (d2 < kd) || (d2 == kd && p < ki);
    unsigned long long mask = __ballot(cand);
    while (mask) {
        const int l = __ffsll(mask) - 1;
        mask &= mask - 1;
        const float dc = __shfl(d2, l);
        const int   pc = __shfl(p, l);
        if ((dc < kd) || (dc == kd && pc < ki)) {
            const bool before = (ld < dc) || (ld == dc && li < pc);
            const int pos = (int)__popcll(__ballot(before));
            const float sd = __shfl_up(ld, 1);
            const int   si = __shfl_up(li, 1);
            if (lane == pos)      { ld = dc; li = pc; }
            else if (lane > pos)  { ld = sd; li = si; }
            if (lane >= KNN_K)    { ld = __builtin_inff(); li = 0x7fffffff; }
            kd = __shfl(ld, KNN_K - 1);
            ki = __shfl(li, KNN_K - 1);
        }
    }
}

// ---------------------------------------------------------------------------
// Kernel 2: 32-NN in 7-D + gather/recenter. One wave per group.
// SoA path: 7+1 coalesced dword loads per 64-point batch. d2 = (c2+x2)-2*dot.
// ---------------------------------------------------------------------------
__global__ __launch_bounds__(256) void knn_kernel(const float* __restrict__ xyz,
                                                  const float* __restrict__ x2,
                                                  const float* __restrict__ xt,
                                                  float* __restrict__ out) {
#pragma clang fp contract(off)
    const int lane = threadIdx.x & 63;
    const int gg = blockIdx.x * 4 + (threadIdx.x >> 6);   // global group 0..8191
    const int b  = gg >> 10;
    const float* X = xyz + (size_t)b * N_PTS * ATTR;

    const float* C = out + OFF_CATTR + (size_t)gg * ATTR;
    const float c0 = C[0], c1 = C[1], c2a = C[2], c3 = C[3], c4 = C[4], c5 = C[5], c6 = C[6];
    float csq = c0 * c0;
    csq = csq + c1 * c1;
    csq = csq + c2a * c2a;
    csq = csq + c3 * c3;
    csq = csq + c4 * c4;
    csq = csq + c5 * c5;
    csq = csq + c6 * c6;

    float ld = __builtin_inff();
    int   li = 0x7fffffff;
    float kd = __builtin_inff();
    int   ki = 0x7fffffff;

    if (xt != nullptr) {
        const float* T0 = xt + (size_t)b * ATTR * N_PTS;
        const float* T1 = T0 + N_PTS;
        const float* T2 = T1 + N_PTS;
        const float* T3 = T2 + N_PTS;
        const float* T4 = T3 + N_PTS;
        const float* T5 = T4 + N_PTS;
        const float* T6 = T5 + N_PTS;
        const float* XB = x2 + (size_t)b * N_PTS;
        for (int p0 = 0; p0 < N_PTS; p0 += 64) {
            const int p = p0 + lane;
            const float q0 = T0[p], q1 = T1[p], q2 = T2[p], q3 = T3[p];
            const float q4 = T4[p], q5 = T5[p], q6 = T6[p];
            float dot = c0 * q0;
            dot = dot + c1 * q1;
            dot = dot + c2a * q2;
            dot = dot + c3 * q3;
            dot = dot + c4 * q4;
            dot = dot + c5 * q5;
            dot = dot + c6 * q6;
            const float xx = XB[p];
            const float d2 = (csq + xx) - 2.0f * dot;
            topk_insert(d2, p, lane, ld, li, kd, ki);
        }
    } else {
        for (int p0 = 0; p0 < N_PTS; p0 += 64) {
            const int p = p0 + lane;
            const float* q = X + (size_t)p * ATTR;
            float dot = c0 * q[0];
            dot = dot + c1 * q[1];
            dot = dot + c2a * q[2];
            dot = dot + c3 * q[3];
            dot = dot + c4 * q[4];
            dot = dot + c5 * q[5];
            dot = dot + c6 * q[6];
            float xx = q[0] * q[0];
            xx = xx + q[1] * q[1];
            xx = xx + q[2] * q[2];
            xx = xx + q[3] * q[3];
            xx = xx + q[4] * q[4];
            xx = xx + q[5] * q[5];
            xx = xx + q[6] * q[6];
            const float d2 = (csq + xx) - 2.0f * dot;
            topk_insert(d2, p, lane, ld, li, kd, ki);
        }
    }

    // neighborhood output: lane j writes rank-j neighbor (ascending (d2,idx))
    if (lane < KNN_K) {
        const float* q = X + (size_t)li * ATTR;
        float* o = out + OFF_NB + ((size_t)gg * KNN_K + lane) * ATTR;
        o[0] = q[0] - c0;
        o[1] = q[1] - c1;
        o[2] = q[2] - c2a;
        o[3] = q[3];
        o[4] = q[4];
        o[5] = q[5];
        o[6] = q[6];
    }
}

extern "C" void kernel_launch(void* const* d_in, const int* in_sizes, int n_in,
                              void* d_out, int out_size, void* d_ws, size_t ws_size,
                              hipStream_t stream) {
    const float* xyz = (const float*)d_in[0];
    float* out = (float*)d_out;

    const size_t need = (size_t)(B_SZ * N_PTS) * (1 + ATTR) * sizeof(float);  // 4 MiB
    const bool use_ws = ws_size >= need;
    float* x2 = use_ws ? (float*)d_ws : nullptr;
    float* xt = use_ws ? ((float*)d_ws + B_SZ * N_PTS) : nullptr;

    if (use_ws) {
        prep_kernel<<<(B_SZ * N_PTS + 255) / 256, 256, 0, stream>>>(xyz, x2, xt);
    }
    fps_kernel<<<B_SZ, 512, 0, stream>>>(xyz, out);
    knn_kernel<<<(B_SZ * NGROUP) / 4, 256, 0, stream>>>(xyz, x2, xt, out);
}

// Round 6
// 2056.096 us; speedup vs baseline: 1.0066x; 1.0066x over previous
//
#include <hip/hip_runtime.h>

#define N_PTS  16384
#define B_SZ   8
#define NGROUP 1024
#define KNN_K  32
#define ATTR   7

// d_out layout (floats), reference return order:
// neighborhood (8,1024,32,7), center_idx (8,1024), centroids_attrs (8,1024,7), centroids_coors (8,1024,3)
#define OFF_NB     0
#define OFF_IDX    (B_SZ * NGROUP * KNN_K * ATTR)            // 1835008
#define OFF_CATTR  (OFF_IDX + B_SZ * NGROUP)                 // 1843200
#define OFF_CCOORD (OFF_CATTR + B_SZ * NGROUP * ATTR)        // 1900544

typedef float v2f __attribute__((ext_vector_type(2)));                 // packed-f32 math
typedef float f2u __attribute__((ext_vector_type(2), aligned(4)));     // 4B-aligned vec load

// ---------------------------------------------------------------------------
// DPP 64-lane reductions (VALU-only; no DS-pipe traffic).
// ---------------------------------------------------------------------------
template <int CTRL>
__device__ __forceinline__ float fmax_dpp_step(float x) {
    int d = __builtin_amdgcn_update_dpp(__float_as_int(x), __float_as_int(x),
                                        CTRL, 0xf, 0xf, false);
    return fmaxf(x, __int_as_float(d));
}
template <int CTRL>
__device__ __forceinline__ unsigned umin_dpp_step(unsigned x) {
    unsigned d = (unsigned)__builtin_amdgcn_update_dpp((int)x, (int)x,
                                                       CTRL, 0xf, 0xf, false);
    return x < d ? x : d;
}

__device__ __forceinline__ float wave_max_f32(float x) {
    x = fmax_dpp_step<0x111>(x);   // row_shr:1
    x = fmax_dpp_step<0x112>(x);   // row_shr:2
    x = fmax_dpp_step<0x114>(x);   // row_shr:4
    x = fmax_dpp_step<0x118>(x);   // row_shr:8
    x = fmax_dpp_step<0x142>(x);   // row_bcast15
    x = fmax_dpp_step<0x143>(x);   // row_bcast31 -> lane63 = full-wave max
    return __int_as_float(__builtin_amdgcn_readlane(__float_as_int(x), 63));
}
__device__ __forceinline__ unsigned wave_min_u32(unsigned x) {
    x = umin_dpp_step<0x111>(x);
    x = umin_dpp_step<0x112>(x);
    x = umin_dpp_step<0x114>(x);
    x = umin_dpp_step<0x118>(x);
    x = umin_dpp_step<0x142>(x);
    x = umin_dpp_step<0x143>(x);
    return (unsigned)__builtin_amdgcn_readlane((int)x, 63);
}

// ---------------------------------------------------------------------------
// Kernel 0: prep — x2[b][n] = sum_a xyz[b][n][a]^2 (sequential, no FMA) and
// SoA transpose xt[b][a][n] for coalesced KNN reads.
// ---------------------------------------------------------------------------
__global__ void prep_kernel(const float* __restrict__ xyz, float* __restrict__ x2,
                            float* __restrict__ xt) {
#pragma clang fp contract(off)
    int i = blockIdx.x * blockDim.x + threadIdx.x;
    if (i >= B_SZ * N_PTS) return;
    const int b = i >> 14;
    const int p = i & (N_PTS - 1);
    const float* q = xyz + (size_t)i * ATTR;
    f2u a01 = *(const f2u*)q;
    f2u a23 = *(const f2u*)(q + 2);
    f2u a45 = *(const f2u*)(q + 4);
    float a6 = q[6];
    float s = a01.x * a01.x;
    s = s + a01.y * a01.y;
    s = s + a23.x * a23.x;
    s = s + a23.y * a23.y;
    s = s + a45.x * a45.x;
    s = s + a45.y * a45.y;
    s = s + a6 * a6;
    x2[i] = s;
    float* T = xt + (size_t)b * ATTR * N_PTS + p;
    T[0 * N_PTS] = a01.x;
    T[1 * N_PTS] = a01.y;
    T[2 * N_PTS] = a23.x;
    T[3 * N_PTS] = a23.y;
    T[4 * N_PTS] = a45.x;
    T[5 * N_PTS] = a45.y;
    T[6 * N_PTS] = a6;
}

// ---------------------------------------------------------------------------
// Kernel 1: farthest point sampling. One 1024-thread block per batch
// (16 waves/CU = 4/SIMD — 2x the latency hiding of the 512-thr versions).
// Per-step time was ~invariant across scratch/LDS/reg data paths in rounds
// 2-5 => cost is VALU issue + serial tail at low wave count, not storage.
// All point data in REGISTERS: 8 v2f per plane (x,y,z,d) = 64 VGPRs data.
//   * amdgpu_waves_per_eu(4,4): RA budget 128 VGPR == real occupancy
//     (1 block/CU since only 8 blocks exist). Kills round-1's 8-wave
//     register-target that caused the invariant-coord spill (VGPR=40).
//   * per-iteration empty-asm "+v" pins on px/py/pz: redefined every step
//     -> not rematerializable, spill = per-step RMW (RA keeps them).
// Math sequence identical to rounds 1-5 (unfused, sequential, contract off);
// pair mapping (2q,2q+1), per-thread ascending scan order -> np.argmax
// first-max-wins tie semantics preserved exactly.
// ---------------------------------------------------------------------------
#define FOR8(M) M(0) M(1) M(2) M(3) M(4) M(5) M(6) M(7)

#define PT_DECL(J) v2f px##J, py##J, pz##J, pd##J;

#define PT_LOAD(J) { \
    const int q = t + (J << 10); \
    const float* r0 = X + (size_t)(q << 1) * ATTR; \
    f2u u0 = *(const f2u*)r0;          float z0 = r0[2]; \
    f2u u1 = *(const f2u*)(r0 + ATTR); float z1 = r0[2 + ATTR]; \
    px##J = (v2f){u0.x, u1.x}; \
    py##J = (v2f){u0.y, u1.y}; \
    pz##J = (v2f){z0, z1}; \
    pd##J = (v2f){1e10f, 1e10f}; }

#define PT_STEP(J) { \
    v2f dx = px##J - cx2; \
    v2f dy = py##J - cy2; \
    v2f dz = pz##J - cz2; \
    v2f a  = dx * dx; \
    a = a + dy * dy; \
    a = a + dz * dz; \
    v2f nd; \
    nd.x = fminf(pd##J.x, a.x); \
    nd.y = fminf(pd##J.y, a.y); \
    pd##J = nd; \
    if (nd.x > best) { best = nd.x; bidx = (t << 1) + (J << 11); } \
    if (nd.y > best) { best = nd.y; bidx = (t << 1) + (J << 11) + 1; } }

__global__ __launch_bounds__(1024)
__attribute__((amdgpu_waves_per_eu(4, 4)))
void fps_kernel(const float* __restrict__ xyz, float* __restrict__ out) {
#pragma clang fp contract(off)
    const int b = blockIdx.x;
    const int t = threadIdx.x;
    const int lane = t & 63;
    const int w = t >> 6;                      // wave 0..15
    const float* X = xyz + (size_t)b * N_PTS * ATTR;

    FOR8(PT_DECL)
    FOR8(PT_LOAD)

    __shared__ unsigned long long sbuf[2][16];
    __shared__ int sel[NGROUP];
    if (t == 0) sel[0] = 0;
    float cx = X[0], cy = X[1], cz = X[2];     // farthest=0 initial centroid
    __syncthreads();

    for (int s = 0; s < NGROUP - 1; ++s) {
        const int par = s & 1;
        // pin the invariant coord planes: redefined each iteration ->
        // cannot be rematerialized; spilling them would cost per-step RMW.
        asm volatile("" : "+v"(px0), "+v"(px1), "+v"(px2), "+v"(px3),
                          "+v"(px4), "+v"(px5), "+v"(px6), "+v"(px7));
        asm volatile("" : "+v"(py0), "+v"(py1), "+v"(py2), "+v"(py3),
                          "+v"(py4), "+v"(py5), "+v"(py6), "+v"(py7));
        asm volatile("" : "+v"(pz0), "+v"(pz1), "+v"(pz2), "+v"(pz3),
                          "+v"(pz4), "+v"(pz5), "+v"(pz6), "+v"(pz7));
        const v2f cx2 = {cx, cx}, cy2 = {cy, cy}, cz2 = {cz, cz};
        float best = -1.0f;
        int   bidx = 0;
        // strict '>' + per-thread ascending scan order == np.argmax semantics.
        FOR8(PT_STEP)
        // wave-level: max distance, then smallest point index among exact ties.
        const float wm = wave_max_f32(best);
        const unsigned cand = (best == wm) ? (unsigned)bidx : 0xFFFFFFFFu;
        const unsigned widx = wave_min_u32(cand);
        if (lane == 0) {
            // d >= 0 so float bits are order-preserving as u32.
            sbuf[par][w] = ((unsigned long long)__float_as_uint(wm) << 32) |
                           (unsigned)(N_PTS - widx);
        }
        __syncthreads();
        // every thread combines the 16 wave keys (uniform broadcast reads).
        unsigned long long bk = sbuf[par][0];
#pragma unroll
        for (int i = 1; i < 16; ++i) {
            const unsigned long long k = sbuf[par][i];
            if (k > bk) bk = k;
        }
        const int win = N_PTS - (int)(unsigned)bk;
        const int sbidx = __builtin_amdgcn_readfirstlane(win);
        if (t == 0) sel[s + 1] = sbidx;
        // uniform (SGPR) address -> scalar load of winner coords, L2-hit.
        const float* q = X + (size_t)sbidx * ATTR;
        cx = q[0]; cy = q[1]; cz = q[2];
    }
    __syncthreads();

    // outputs: center_idx, centroids_attrs, centroids_coors (1024 threads = 1024 groups)
    {
        const int g = t;
        const int idx = sel[g];
        const float* q = X + (size_t)idx * ATTR;
        float a0 = q[0], a1 = q[1], a2 = q[2], a3 = q[3], a4 = q[4], a5 = q[5], a6 = q[6];
        out[OFF_IDX + b * NGROUP + g] = (float)idx;
        float* ca = out + OFF_CATTR + (size_t)(b * NGROUP + g) * ATTR;
        ca[0] = a0; ca[1] = a1; ca[2] = a2; ca[3] = a3; ca[4] = a4; ca[5] = a5; ca[6] = a6;
        float* cc = out + OFF_CCOORD + (size_t)(b * NGROUP + g) * 3;
        cc[0] = a0; cc[1] = a1; cc[2] = a2;
    }
}

// ---------------------------------------------------------------------------
// distributed top-32 insert (sorted list lives one-slot-per-lane, lanes 0..31)
// ---------------------------------------------------------------------------
__device__ __forceinline__ void topk_insert(float d2, int p, int lane,
                                            float& ld, int& li, float& kd, int& ki) {
    const bool cand = (d2 < kd) || (d2 == kd && p < ki);
    unsigned long long mask = __ballot(cand);
    while (mask) {
        const int l = __ffsll(mask) - 1;
        mask &= mask - 1;
        const float dc = __shfl(d2, l);
        const int   pc = __shfl(p, l);
        if ((dc < kd) || (dc == kd && pc < ki)) {
            const bool before = (ld < dc) || (ld == dc && li < pc);
            const int pos = (int)__popcll(__ballot(before));
            const float sd = __shfl_up(ld, 1);
            const int   si = __shfl_up(li, 1);
            if (lane == pos)      { ld = dc; li = pc; }
            else if (lane > pos)  { ld = sd; li = si; }
            if (lane >= KNN_K)    { ld = __builtin_inff(); li = 0x7fffffff; }
            kd = __shfl(ld, KNN_K - 1);
            ki = __shfl(li, KNN_K - 1);
        }
    }
}

// ---------------------------------------------------------------------------
// Kernel 2: 32-NN in 7-D + gather/recenter. One wave per group.
// SoA path: 7+1 coalesced dword loads per 64-point batch. d2 = (c2+x2)-2*dot.
// ---------------------------------------------------------------------------
__global__ __launch_bounds__(256) void knn_kernel(const float* __restrict__ xyz,
                                                  const float* __restrict__ x2,
                                                  const float* __restrict__ xt,
                                                  float* __restrict__ out) {
#pragma clang fp contract(off)
    const int lane = threadIdx.x & 63;
    const int gg = blockIdx.x * 4 + (threadIdx.x >> 6);   // global group 0..8191
    const int b  = gg >> 10;
    const float* X = xyz + (size_t)b * N_PTS * ATTR;

    const float* C = out + OFF_CATTR + (size_t)gg * ATTR;
    const float c0 = C[0], c1 = C[1], c2a = C[2], c3 = C[3], c4 = C[4], c5 = C[5], c6 = C[6];
    float csq = c0 * c0;
    csq = csq + c1 * c1;
    csq = csq + c2a * c2a;
    csq = csq + c3 * c3;
    csq = csq + c4 * c4;
    csq = csq + c5 * c5;
    csq = csq + c6 * c6;

    float ld = __builtin_inff();
    int   li = 0x7fffffff;
    float kd = __builtin_inff();
    int   ki = 0x7fffffff;

    if (xt != nullptr) {
        const float* T0 = xt + (size_t)b * ATTR * N_PTS;
        const float* T1 = T0 + N_PTS;
        const float* T2 = T1 + N_PTS;
        const float* T3 = T2 + N_PTS;
        const float* T4 = T3 + N_PTS;
        const float* T5 = T4 + N_PTS;
        const float* T6 = T5 + N_PTS;
        const float* XB = x2 + (size_t)b * N_PTS;
        for (int p0 = 0; p0 < N_PTS; p0 += 64) {
            const int p = p0 + lane;
            const float q0 = T0[p], q1 = T1[p], q2 = T2[p], q3 = T3[p];
            const float q4 = T4[p], q5 = T5[p], q6 = T6[p];
            float dot = c0 * q0;
            dot = dot + c1 * q1;
            dot = dot + c2a * q2;
            dot = dot + c3 * q3;
            dot = dot + c4 * q4;
            dot = dot + c5 * q5;
            dot = dot + c6 * q6;
            const float xx = XB[p];
            const float d2 = (csq + xx) - 2.0f * dot;
            topk_insert(d2, p, lane, ld, li, kd, ki);
        }
    } else {
        for (int p0 = 0; p0 < N_PTS; p0 += 64) {
            const int p = p0 + lane;
            const float* q = X + (size_t)p * ATTR;
            float dot = c0 * q[0];
            dot = dot + c1 * q[1];
            dot = dot + c2a * q[2];
            dot = dot + c3 * q[3];
            dot = dot + c4 * q[4];
            dot = dot + c5 * q[5];
            dot = dot + c6 * q[6];
            float xx = q[0] * q[0];
            xx = xx + q[1] * q[1];
            xx = xx + q[2] * q[2];
            xx = xx + q[3] * q[3];
            xx = xx + q[4] * q[4];
            xx = xx + q[5] * q[5];
            xx = xx + q[6] * q[6];
            const float d2 = (csq + xx) - 2.0f * dot;
            topk_insert(d2, p, lane, ld, li, kd, ki);
        }
    }

    // neighborhood output: lane j writes rank-j neighbor (ascending (d2,idx))
    if (lane < KNN_K) {
        const float* q = X + (size_t)li * ATTR;
        float* o = out + OFF_NB + ((size_t)gg * KNN_K + lane) * ATTR;
        o[0] = q[0] - c0;
        o[1] = q[1] - c1;
        o[2] = q[2] - c2a;
        o[3] = q[3];
        o[4] = q[4];
        o[5] = q[5];
        o[6] = q[6];
    }
}

extern "C" void kernel_launch(void* const* d_in, const int* in_sizes, int n_in,
                              void* d_out, int out_size, void* d_ws, size_t ws_size,
                              hipStream_t stream) {
    const float* xyz = (const float*)d_in[0];
    float* out = (float*)d_out;

    const size_t need = (size_t)(B_SZ * N_PTS) * (1 + ATTR) * sizeof(float);  // 4 MiB
    const bool use_ws = ws_size >= need;
    float* x2 = use_ws ? (float*)d_ws : nullptr;
    float* xt = use_ws ? ((float*)d_ws + B_SZ * N_PTS) : nullptr;

    if (use_ws) {
        prep_kernel<<<(B_SZ * N_PTS + 255) / 256, 256, 0, stream>>>(xyz, x2, xt);
    }
    fps_kernel<<<B_SZ, 1024, 0, stream>>>(xyz, out);
    knn_kernel<<<(B_SZ * NGROUP) / 4, 256, 0, stream>>>(xyz, x2, xt, out);
}

// Round 8
// 2036.116 us; speedup vs baseline: 1.0165x; 1.0098x over previous
//
#include <hip/hip_runtime.h>

#define N_PTS  16384
#define B_SZ   8
#define NGROUP 1024
#define KNN_K  32
#define ATTR   7

// d_out layout (floats), reference return order:
// neighborhood (8,1024,32,7), center_idx (8,1024), centroids_attrs (8,1024,7), centroids_coors (8,1024,3)
#define OFF_NB     0
#define OFF_IDX    (B_SZ * NGROUP * KNN_K * ATTR)            // 1835008
#define OFF_CATTR  (OFF_IDX + B_SZ * NGROUP)                 // 1843200
#define OFF_CCOORD (OFF_CATTR + B_SZ * NGROUP * ATTR)        // 1900544

typedef float v2f __attribute__((ext_vector_type(2)));                 // packed-f32 math
typedef float v4f __attribute__((ext_vector_type(4)));                 // LDS 16B tile
typedef float f2u __attribute__((ext_vector_type(2), aligned(4)));     // 4B-aligned vec load

// ---------------------------------------------------------------------------
// DPP 64-lane reductions (VALU-only; no DS-pipe traffic).
// ---------------------------------------------------------------------------
template <int CTRL>
__device__ __forceinline__ float fmax_dpp_step(float x) {
    int d = __builtin_amdgcn_update_dpp(__float_as_int(x), __float_as_int(x),
                                        CTRL, 0xf, 0xf, false);
    return fmaxf(x, __int_as_float(d));
}
template <int CTRL>
__device__ __forceinline__ unsigned umin_dpp_step(unsigned x) {
    unsigned d = (unsigned)__builtin_amdgcn_update_dpp((int)x, (int)x,
                                                       CTRL, 0xf, 0xf, false);
    return x < d ? x : d;
}

__device__ __forceinline__ float wave_max_f32(float x) {
    x = fmax_dpp_step<0x111>(x);   // row_shr:1
    x = fmax_dpp_step<0x112>(x);   // row_shr:2
    x = fmax_dpp_step<0x114>(x);   // row_shr:4
    x = fmax_dpp_step<0x118>(x);   // row_shr:8
    x = fmax_dpp_step<0x142>(x);   // row_bcast15
    x = fmax_dpp_step<0x143>(x);   // row_bcast31 -> lane63 = full-wave max
    return __int_as_float(__builtin_amdgcn_readlane(__float_as_int(x), 63));
}
__device__ __forceinline__ unsigned wave_min_u32(unsigned x) {
    x = umin_dpp_step<0x111>(x);
    x = umin_dpp_step<0x112>(x);
    x = umin_dpp_step<0x114>(x);
    x = umin_dpp_step<0x118>(x);
    x = umin_dpp_step<0x142>(x);
    x = umin_dpp_step<0x143>(x);
    return (unsigned)__builtin_amdgcn_readlane((int)x, 63);
}

// ---------------------------------------------------------------------------
// Kernel 0: prep — x2[b][n] = sum_a xyz[b][n][a]^2 (sequential, no FMA) and
// SoA transpose xt[b][a][n] for coalesced KNN reads.
// ---------------------------------------------------------------------------
__global__ void prep_kernel(const float* __restrict__ xyz, float* __restrict__ x2,
                            float* __restrict__ xt) {
#pragma clang fp contract(off)
    int i = blockIdx.x * blockDim.x + threadIdx.x;
    if (i >= B_SZ * N_PTS) return;
    const int b = i >> 14;
    const int p = i & (N_PTS - 1);
    const float* q = xyz + (size_t)i * ATTR;
    f2u a01 = *(const f2u*)q;
    f2u a23 = *(const f2u*)(q + 2);
    f2u a45 = *(const f2u*)(q + 4);
    float a6 = q[6];
    float s = a01.x * a01.x;
    s = s + a01.y * a01.y;
    s = s + a23.x * a23.x;
    s = s + a23.y * a23.y;
    s = s + a45.x * a45.x;
    s = s + a45.y * a45.y;
    s = s + a6 * a6;
    x2[i] = s;
    float* T = xt + (size_t)b * ATTR * N_PTS + p;
    T[0 * N_PTS] = a01.x;
    T[1 * N_PTS] = a01.y;
    T[2 * N_PTS] = a23.x;
    T[3 * N_PTS] = a23.y;
    T[4 * N_PTS] = a45.x;
    T[5 * N_PTS] = a45.y;
    T[6 * N_PTS] = a6;
}

// ---------------------------------------------------------------------------
// Kernel 1: farthest point sampling. One 1024-thread block per batch.
// R1-R6 lesson: per-step time was storage-invariant because the active CUs
// are VALU-ISSUE bound (VALUBusy*256/8 ~ 94%) and RA's AGPR spill shuffling
// (incl. our own "+v" pins forcing accvgpr moves) doubled the issue count.
// R7: give every byte an explicit, cheap home; minimize per-step VALU.
//   * x,y planes in LDS as {x0,x1,y0,y1} float4 tiles (128 KB): 8
//     conflict-free ds_read_b128/thread/step on the DS pipe (overlaps VALU).
//     132 KB LDS caps occupancy at 1 block/CU; RA's own occupancy calc then
//     yields a 128-VGPR budget (R5 proved: 135.7 KB static LDS runs fine).
//   * z + pd in named registers: only 32 VGPRs — far under budget. No pins.
//   * block combine via single triple-buffered LDS atomicMax (round-0
//     scheme): ~2 insts/thread instead of a 16-slot u64 scan (~70 insts).
// Math sequence identical (unfused, sequential, contract off). Pair mapping
// (2q,2q+1), per-thread ascending scan order, strict '>', wave umin on tie,
// atomicMax key (d-bits<<32 | 16384-idx) -> np.argmax first-max-wins exact.
// ---------------------------------------------------------------------------
#define FOR8(M) M(0) M(1) M(2) M(3) M(4) M(5) M(6) M(7)

#define PT_DECL(J) v2f pz##J, pd##J;

#define STAGE(J) { \
    const int q = t + (J << 10); \
    const float* r0 = X + (size_t)(q << 1) * ATTR; \
    f2u u0 = *(const f2u*)r0;          float z0 = r0[2]; \
    f2u u1 = *(const f2u*)(r0 + ATTR); float z1 = r0[2 + ATTR]; \
    lxy[q] = (v4f){u0.x, u1.x, u0.y, u1.y}; \
    pz##J = (v2f){z0, z1}; \
    pd##J = (v2f){1e10f, 1e10f}; }

#define PT_STEP(J) { \
    const v4f xy = lxy[t + (J << 10)]; \
    v2f dx = (v2f){xy.x, xy.y} - cx2; \
    v2f dy = (v2f){xy.z, xy.w} - cy2; \
    v2f dz = pz##J - cz2; \
    v2f a  = dx * dx; \
    a = a + dy * dy; \
    a = a + dz * dz; \
    v2f nd; \
    nd.x = fminf(pd##J.x, a.x); \
    nd.y = fminf(pd##J.y, a.y); \
    pd##J = nd; \
    if (nd.x > best) { best = nd.x; bidx = (t << 1) + (J << 11); } \
    if (nd.y > best) { best = nd.y; bidx = (t << 1) + (J << 11) + 1; } }

__global__ __launch_bounds__(1024)
void fps_kernel(const float* __restrict__ xyz, float* __restrict__ out) {
#pragma clang fp contract(off)
    const int b = blockIdx.x;
    const int t = threadIdx.x;
    const int lane = t & 63;
    const float* X = xyz + (size_t)b * N_PTS * ATTR;

    __shared__ v4f lxy[N_PTS / 2];             // {x0,x1,y0,y1} per pair (128 KB)
    __shared__ int sel[NGROUP];                // (4 KB)
    __shared__ unsigned long long slot[3];     // triple-buffered combine slot

    FOR8(PT_DECL)
    FOR8(STAGE)

    if (t == 0) { slot[0] = 0ull; sel[0] = 0; }
    float cx = X[0], cy = X[1], cz = X[2];     // farthest=0 initial centroid
    __syncthreads();

    for (int s = 0; s < NGROUP - 1; ++s) {
        const v2f cx2 = {cx, cx}, cy2 = {cy, cy}, cz2 = {cz, cz};
        float best = -1.0f;
        int   bidx = 0;
        // strict '>' + per-thread ascending scan order == np.argmax semantics.
        FOR8(PT_STEP)
        // wave-level: max distance, then smallest point index among exact ties.
        const float wm = wave_max_f32(best);
        const unsigned cand = (best == wm) ? (unsigned)bidx : 0xFFFFFFFFu;
        const unsigned widx = wave_min_u32(cand);
        // monotone key: larger d wins; tie -> smaller index (larger 16384-idx).
        // d >= 0 always, so float bits are order-preserving as u32.
        if (lane == 0) {
            const unsigned long long key =
                ((unsigned long long)__float_as_uint(wm) << 32) |
                (unsigned)(N_PTS - widx);
            atomicMax(&slot[s % 3], key);
        }
        // reset the NEXT step's slot now: reads of this slot happened at step
        // s-2 (before barrier s-1); next step's atomics happen after barrier s.
        if (t == 0) slot[(s + 1) % 3] = 0ull;
        __syncthreads();
        const unsigned long long bk = slot[s % 3];
        const int win = N_PTS - (int)(unsigned)bk;
        const int sbidx = __builtin_amdgcn_readfirstlane(win);
        if (t == 0) sel[s + 1] = sbidx;
        // uniform (SGPR) address -> scalar load of winner coords, L2-hit.
        const float* q = X + (size_t)sbidx * ATTR;
        cx = q[0]; cy = q[1]; cz = q[2];
    }
    __syncthreads();

    // outputs: center_idx, centroids_attrs, centroids_coors (1024 threads = 1024 groups)
    {
        const int g = t;
        const int idx = sel[g];
        const float* q = X + (size_t)idx * ATTR;
        float a0 = q[0], a1 = q[1], a2 = q[2], a3 = q[3], a4 = q[4], a5 = q[5], a6 = q[6];
        out[OFF_IDX + b * NGROUP + g] = (float)idx;
        float* ca = out + OFF_CATTR + (size_t)(b * NGROUP + g) * ATTR;
        ca[0] = a0; ca[1] = a1; ca[2] = a2; ca[3] = a3; ca[4] = a4; ca[5] = a5; ca[6] = a6;
        float* cc = out + OFF_CCOORD + (size_t)(b * NGROUP + g) * 3;
        cc[0] = a0; cc[1] = a1; cc[2] = a2;
    }
}

// ---------------------------------------------------------------------------
// distributed top-32 insert (sorted list lives one-slot-per-lane, lanes 0..31)
// ---------------------------------------------------------------------------
__device__ __forceinline__ void topk_insert(float d2, int p, int lane,
                                            float& ld, int& li, float& kd, int& ki) {
    const bool cand = (d2 < kd) || (d2 == kd && p < ki);
    unsigned long long mask = __ballot(cand);
    while (mask) {
        const int l = __ffsll(mask) - 1;
        mask &= mask - 1;
        const float dc = __shfl(d2, l);
        const int   pc = __shfl(p, l);
        if ((dc < kd) || (dc == kd && pc < ki)) {
            const bool before = (ld < dc) || (ld == dc && li < pc);
            const int pos = (int)__popcll(__ballot(before));
            const float sd = __shfl_up(ld, 1);
            const int   si = __shfl_up(li, 1);
            if (lane == pos)      { ld = dc; li = pc; }
            else if (lane > pos)  { ld = sd; li = si; }
            if (lane >= KNN_K)    { ld = __builtin_inff(); li = 0x7fffffff; }
            kd = __shfl(ld, KNN_K - 1);
            ki = __shfl(li, KNN_K - 1);
        }
    }
}

// ---------------------------------------------------------------------------
// Kernel 2: 32-NN in 7-D + gather/recenter. One wave per group.
// SoA path: 7+1 coalesced dword loads per 64-point batch. d2 = (c2+x2)-2*dot.
// ---------------------------------------------------------------------------
__global__ __launch_bounds__(256) void knn_kernel(const float* __restrict__ xyz,
                                                  const float* __restrict__ x2,
                                                  const float* __restrict__ xt,
                                                  float* __restrict__ out) {
#pragma clang fp contract(off)
    const int lane = threadIdx.x & 63;
    const int gg = blockIdx.x * 4 + (threadIdx.x >> 6);   // global group 0..8191
    const int b  = gg >> 10;
    const float* X = xyz + (size_t)b * N_PTS * ATTR;

    const float* C = out + OFF_CATTR + (size_t)gg * ATTR;
    const float c0 = C[0], c1 = C[1], c2a = C[2], c3 = C[3], c4 = C[4], c5 = C[5], c6 = C[6];
    float csq = c0 * c0;
    csq = csq + c1 * c1;
    csq = csq + c2a * c2a;
    csq = csq + c3 * c3;
    csq = csq + c4 * c4;
    csq = csq + c5 * c5;
    csq = csq + c6 * c6;

    float ld = __builtin_inff();
    int   li = 0x7fffffff;
    float kd = __builtin_inff();
    int   ki = 0x7fffffff;

    if (xt != nullptr) {
        const float* T0 = xt + (size_t)b * ATTR * N_PTS;
        const float* T1 = T0 + N_PTS;
        const float* T2 = T1 + N_PTS;
        const float* T3 = T2 + N_PTS;
        const float* T4 = T3 + N_PTS;
        const float* T5 = T4 + N_PTS;
        const float* T6 = T5 + N_PTS;
        const float* XB = x2 + (size_t)b * N_PTS;
        for (int p0 = 0; p0 < N_PTS; p0 += 64) {
            const int p = p0 + lane;
            const float q0 = T0[p], q1 = T1[p], q2 = T2[p], q3 = T3[p];
            const float q4 = T4[p], q5 = T5[p], q6 = T6[p];
            float dot = c0 * q0;
            dot = dot + c1 * q1;
            dot = dot + c2a * q2;
            dot = dot + c3 * q3;
            dot = dot + c4 * q4;
            dot = dot + c5 * q5;
            dot = dot + c6 * q6;
            const float xx = XB[p];
            const float d2 = (csq + xx) - 2.0f * dot;
            topk_insert(d2, p, lane, ld, li, kd, ki);
        }
    } else {
        for (int p0 = 0; p0 < N_PTS; p0 += 64) {
            const int p = p0 + lane;
            const float* q = X + (size_t)p * ATTR;
            float dot = c0 * q[0];
            dot = dot + c1 * q[1];
            dot = dot + c2a * q[2];
            dot = dot + c3 * q[3];
            dot = dot + c4 * q[4];
            dot = dot + c5 * q[5];
            dot = dot + c6 * q[6];
            float xx = q[0] * q[0];
            xx = xx + q[1] * q[1];
            xx = xx + q[2] * q[2];
            xx = xx + q[3] * q[3];
            xx = xx + q[4] * q[4];
            xx = xx + q[5] * q[5];
            xx = xx + q[6] * q[6];
            const float d2 = (csq + xx) - 2.0f * dot;
            topk_insert(d2, p, lane, ld, li, kd, ki);
        }
    }

    // neighborhood output: lane j writes rank-j neighbor (ascending (d2,idx))
    if (lane < KNN_K) {
        const float* q = X + (size_t)li * ATTR;
        float* o = out + OFF_NB + ((size_t)gg * KNN_K + lane) * ATTR;
        o[0] = q[0] - c0;
        o[1] = q[1] - c1;
        o[2] = q[2] - c2a;
        o[3] = q[3];
        o[4] = q[4];
        o[5] = q[5];
        o[6] = q[6];
    }
}

extern "C" void kernel_launch(void* const* d_in, const int* in_sizes, int n_in,
                              void* d_out, int out_size, void* d_ws, size_t ws_size,
                              hipStream_t stream) {
    const float* xyz = (const float*)d_in[0];
    float* out = (float*)d_out;

    const size_t need = (size_t)(B_SZ * N_PTS) * (1 + ATTR) * sizeof(float);  // 4 MiB
    const bool use_ws = ws_size >= need;
    float* x2 = use_ws ? (float*)d_ws : nullptr;
    float* xt = use_ws ? ((float*)d_ws + B_SZ * N_PTS) : nullptr;

    if (use_ws) {
        prep_kernel<<<(B_SZ * N_PTS + 255) / 256, 256, 0, stream>>>(xyz, x2, xt);
    }
    fps_kernel<<<B_SZ, 1024, 0, stream>>>(xyz, out);
    knn_kernel<<<(B_SZ * NGROUP) / 4, 256, 0, stream>>>(xyz, x2, xt, out);
}

// Round 9
// 1988.496 us; speedup vs baseline: 1.0408x; 1.0239x over previous
//
#include <hip/hip_runtime.h>

#define N_PTS  16384
#define B_SZ   8
#define NGROUP 1024
#define KNN_K  32
#define ATTR   7

// d_out layout (floats), reference return order:
// neighborhood (8,1024,32,7), center_idx (8,1024), centroids_attrs (8,1024,7), centroids_coors (8,1024,3)
#define OFF_NB     0
#define OFF_IDX    (B_SZ * NGROUP * KNN_K * ATTR)            // 1835008
#define OFF_CATTR  (OFF_IDX + B_SZ * NGROUP)                 // 1843200
#define OFF_CCOORD (OFF_CATTR + B_SZ * NGROUP * ATTR)        // 1900544

typedef float v2f __attribute__((ext_vector_type(2)));                 // packed-f32 math
typedef float v4f __attribute__((ext_vector_type(4)));                 // LDS 16B tile
typedef float f2u __attribute__((ext_vector_type(2), aligned(4)));     // 4B-aligned vec load

// ---------------------------------------------------------------------------
// DPP 64-lane reductions (VALU-only; no DS-pipe traffic).
// ---------------------------------------------------------------------------
template <int CTRL>
__device__ __forceinline__ float fmax_dpp_step(float x) {
    int d = __builtin_amdgcn_update_dpp(__float_as_int(x), __float_as_int(x),
                                        CTRL, 0xf, 0xf, false);
    return fmaxf(x, __int_as_float(d));
}
template <int CTRL>
__device__ __forceinline__ unsigned umin_dpp_step(unsigned x) {
    unsigned d = (unsigned)__builtin_amdgcn_update_dpp((int)x, (int)x,
                                                       CTRL, 0xf, 0xf, false);
    return x < d ? x : d;
}

__device__ __forceinline__ float wave_max_f32(float x) {
    x = fmax_dpp_step<0x111>(x);   // row_shr:1
    x = fmax_dpp_step<0x112>(x);   // row_shr:2
    x = fmax_dpp_step<0x114>(x);   // row_shr:4
    x = fmax_dpp_step<0x118>(x);   // row_shr:8
    x = fmax_dpp_step<0x142>(x);   // row_bcast15
    x = fmax_dpp_step<0x143>(x);   // row_bcast31 -> lane63 = full-wave max
    return __int_as_float(__builtin_amdgcn_readlane(__float_as_int(x), 63));
}
__device__ __forceinline__ unsigned wave_min_u32(unsigned x) {
    x = umin_dpp_step<0x111>(x);
    x = umin_dpp_step<0x112>(x);
    x = umin_dpp_step<0x114>(x);
    x = umin_dpp_step<0x118>(x);
    x = umin_dpp_step<0x142>(x);
    x = umin_dpp_step<0x143>(x);
    return (unsigned)__builtin_amdgcn_readlane((int)x, 63);
}

// ---------------------------------------------------------------------------
// Kernel 0: prep — x2[b][n] = sum_a xyz[b][n][a]^2 (sequential, no FMA) and
// SoA transpose xt[b][a][n] for coalesced KNN reads.
// ---------------------------------------------------------------------------
__global__ void prep_kernel(const float* __restrict__ xyz, float* __restrict__ x2,
                            float* __restrict__ xt) {
#pragma clang fp contract(off)
    int i = blockIdx.x * blockDim.x + threadIdx.x;
    if (i >= B_SZ * N_PTS) return;
    const int b = i >> 14;
    const int p = i & (N_PTS - 1);
    const float* q = xyz + (size_t)i * ATTR;
    f2u a01 = *(const f2u*)q;
    f2u a23 = *(const f2u*)(q + 2);
    f2u a45 = *(const f2u*)(q + 4);
    float a6 = q[6];
    float s = a01.x * a01.x;
    s = s + a01.y * a01.y;
    s = s + a23.x * a23.x;
    s = s + a23.y * a23.y;
    s = s + a45.x * a45.x;
    s = s + a45.y * a45.y;
    s = s + a6 * a6;
    x2[i] = s;
    float* T = xt + (size_t)b * ATTR * N_PTS + p;
    T[0 * N_PTS] = a01.x;
    T[1 * N_PTS] = a01.y;
    T[2 * N_PTS] = a23.x;
    T[3 * N_PTS] = a23.y;
    T[4 * N_PTS] = a45.x;
    T[5 * N_PTS] = a45.y;
    T[6 * N_PTS] = a6;
}

// ---------------------------------------------------------------------------
// Kernel 1: farthest point sampling. One 1024-thread block per batch.
// R8 established: step time ~1.67us is math-issue + DS-chain + tail; the LDS
// xy reads (128 ds_read_b128/CU/step ~ 1536 cyc) sit in the math dependency
// path. R9: the LDS tile is STATIC -> software-pipeline it. Two register
// buffers ra/rb (32 VGPR each): at the top of step s the reads for step s+1
// issue into the idle buffer; the math runs on the current buffer; the
// barrier's lgkmcnt(0) drain lands after ~2000 cyc of math, so DS is free.
// 2-step unrolled loop swaps buffer roles (no runtime indexing — rule #20).
//   * 132 KB LDS -> 1 block/CU -> 16 waves -> RA budget 128 VGPR;
//     demand ~125 (ra 32 + rb 32 + z 16 + pd 16 + temps).
//   * z + pd stay in registers; combine via triple-buffered LDS atomicMax.
// Math sequence identical to R8 (unfused, sequential, contract off). Pair
// mapping (2q,2q+1), ascending scan order, strict '>', wave umin tie-break,
// key (d-bits<<32 | 16384-idx) -> np.argmax first-max-wins exact.
// ---------------------------------------------------------------------------
#define FOR8(M) M(0) M(1) M(2) M(3) M(4) M(5) M(6) M(7)

#define PT_DECL(J) v2f pz##J, pd##J; v4f ra##J, rb##J;

#define STAGE(J) { \
    const int q = t + (J << 10); \
    const float* r0 = X + (size_t)(q << 1) * ATTR; \
    f2u u0 = *(const f2u*)r0;          float z0 = r0[2]; \
    f2u u1 = *(const f2u*)(r0 + ATTR); float z1 = r0[2 + ATTR]; \
    const v4f xy4 = (v4f){u0.x, u1.x, u0.y, u1.y}; \
    lxy[q] = xy4; \
    ra##J = xy4; \
    rb##J = xy4; \
    pz##J = (v2f){z0, z1}; \
    pd##J = (v2f){1e10f, 1e10f}; }

// one pair-group: prefetch next-step xy into RN, do exact-order math on RC.
#define SCAN1(J, RC, RN) { \
    RN##J = lxy[t + (J << 10)]; \
    const v4f xy = RC##J; \
    v2f dx = (v2f){xy.x, xy.y} - cx2; \
    v2f dy = (v2f){xy.z, xy.w} - cy2; \
    v2f dz = pz##J - cz2; \
    v2f a  = dx * dx; \
    a = a + dy * dy; \
    a = a + dz * dz; \
    v2f nd; \
    nd.x = fminf(pd##J.x, a.x); \
    nd.y = fminf(pd##J.y, a.y); \
    pd##J = nd; \
    if (nd.x > best) { best = nd.x; bidx = (t << 1) + (J << 11); } \
    if (nd.y > best) { best = nd.y; bidx = (t << 1) + (J << 11) + 1; } }

#define FPS_SCAN(RC, RN) \
    SCAN1(0, RC, RN) SCAN1(1, RC, RN) SCAN1(2, RC, RN) SCAN1(3, RC, RN) \
    SCAN1(4, RC, RN) SCAN1(5, RC, RN) SCAN1(6, RC, RN) SCAN1(7, RC, RN)

#define FPS_STEP(SVAL, RC, RN) { \
    const int s_ = (SVAL); \
    const v2f cx2 = {cx, cx}, cy2 = {cy, cy}, cz2 = {cz, cz}; \
    float best = -1.0f; \
    int   bidx = 0; \
    FPS_SCAN(RC, RN) \
    const float wm = wave_max_f32(best); \
    const unsigned cand = (best == wm) ? (unsigned)bidx : 0xFFFFFFFFu; \
    const unsigned widx = wave_min_u32(cand); \
    if (lane == 0) { \
        const unsigned long long key = \
            ((unsigned long long)__float_as_uint(wm) << 32) | \
            (unsigned)(N_PTS - widx); \
        atomicMax(&slot[s_ % 3], key); \
    } \
    if (t == 0) slot[(s_ + 1) % 3] = 0ull; \
    __syncthreads(); \
    const unsigned long long bk = slot[s_ % 3]; \
    const int win = N_PTS - (int)(unsigned)bk; \
    const int sbidx = __builtin_amdgcn_readfirstlane(win); \
    if (t == 0) sel[s_ + 1] = sbidx; \
    const float* qw = X + (size_t)sbidx * ATTR; \
    cx = qw[0]; cy = qw[1]; cz = qw[2]; }

__global__ __launch_bounds__(1024)
void fps_kernel(const float* __restrict__ xyz, float* __restrict__ out) {
#pragma clang fp contract(off)
    const int b = blockIdx.x;
    const int t = threadIdx.x;
    const int lane = t & 63;
    const float* X = xyz + (size_t)b * N_PTS * ATTR;

    __shared__ v4f lxy[N_PTS / 2];             // {x0,x1,y0,y1} per pair (128 KB)
    __shared__ int sel[NGROUP];                // (4 KB)
    __shared__ unsigned long long slot[3];     // triple-buffered combine slot

    FOR8(PT_DECL)
    FOR8(STAGE)

    if (t == 0) { slot[0] = 0ull; sel[0] = 0; }
    float cx = X[0], cy = X[1], cz = X[2];     // farthest=0 initial centroid
    __syncthreads();

    // steps 0..1021 in role-swapping pairs, then final step 1022.
    for (int s = 0; s < NGROUP - 2; s += 2) {
        FPS_STEP(s,     ra, rb)
        FPS_STEP(s + 1, rb, ra)
    }
    FPS_STEP(NGROUP - 2, ra, rb)
    __syncthreads();

    // outputs: center_idx, centroids_attrs, centroids_coors (1024 threads = 1024 groups)
    {
        const int g = t;
        const int idx = sel[g];
        const float* q = X + (size_t)idx * ATTR;
        float a0 = q[0], a1 = q[1], a2 = q[2], a3 = q[3], a4 = q[4], a5 = q[5], a6 = q[6];
        out[OFF_IDX + b * NGROUP + g] = (float)idx;
        float* ca = out + OFF_CATTR + (size_t)(b * NGROUP + g) * ATTR;
        ca[0] = a0; ca[1] = a1; ca[2] = a2; ca[3] = a3; ca[4] = a4; ca[5] = a5; ca[6] = a6;
        float* cc = out + OFF_CCOORD + (size_t)(b * NGROUP + g) * 3;
        cc[0] = a0; cc[1] = a1; cc[2] = a2;
    }
}

// ---------------------------------------------------------------------------
// distributed top-32 insert (sorted list lives one-slot-per-lane, lanes 0..31)
// ---------------------------------------------------------------------------
__device__ __forceinline__ void topk_insert(float d2, int p, int lane,
                                            float& ld, int& li, float& kd, int& ki) {
    const bool cand = (d2 < kd) || (d2 == kd && p < ki);
    unsigned long long mask = __ballot(cand);
    while (mask) {
        const int l = __ffsll(mask) - 1;
        mask &= mask - 1;
        const float dc = __shfl(d2, l);
        const int   pc = __shfl(p, l);
        if ((dc < kd) || (dc == kd && pc < ki)) {
            const bool before = (ld < dc) || (ld == dc && li < pc);
            const int pos = (int)__popcll(__ballot(before));
            const float sd = __shfl_up(ld, 1);
            const int   si = __shfl_up(li, 1);
            if (lane == pos)      { ld = dc; li = pc; }
            else if (lane > pos)  { ld = sd; li = si; }
            if (lane >= KNN_K)    { ld = __builtin_inff(); li = 0x7fffffff; }
            kd = __shfl(ld, KNN_K - 1);
            ki = __shfl(li, KNN_K - 1);
        }
    }
}

// ---------------------------------------------------------------------------
// Kernel 2: 32-NN in 7-D + gather/recenter. One wave per group.
// SoA path: 7+1 coalesced dword loads per 64-point batch. d2 = (c2+x2)-2*dot.
// ---------------------------------------------------------------------------
__global__ __launch_bounds__(256) void knn_kernel(const float* __restrict__ xyz,
                                                  const float* __restrict__ x2,
                                                  const float* __restrict__ xt,
                                                  float* __restrict__ out) {
#pragma clang fp contract(off)
    const int lane = threadIdx.x & 63;
    const int gg = blockIdx.x * 4 + (threadIdx.x >> 6);   // global group 0..8191
    const int b  = gg >> 10;
    const float* X = xyz + (size_t)b * N_PTS * ATTR;

    const float* C = out + OFF_CATTR + (size_t)gg * ATTR;
    const float c0 = C[0], c1 = C[1], c2a = C[2], c3 = C[3], c4 = C[4], c5 = C[5], c6 = C[6];
    float csq = c0 * c0;
    csq = csq + c1 * c1;
    csq = csq + c2a * c2a;
    csq = csq + c3 * c3;
    csq = csq + c4 * c4;
    csq = csq + c5 * c5;
    csq = csq + c6 * c6;

    float ld = __builtin_inff();
    int   li = 0x7fffffff;
    float kd = __builtin_inff();
    int   ki = 0x7fffffff;

    if (xt != nullptr) {
        const float* T0 = xt + (size_t)b * ATTR * N_PTS;
        const float* T1 = T0 + N_PTS;
        const float* T2 = T1 + N_PTS;
        const float* T3 = T2 + N_PTS;
        const float* T4 = T3 + N_PTS;
        const float* T5 = T4 + N_PTS;
        const float* T6 = T5 + N_PTS;
        const float* XB = x2 + (size_t)b * N_PTS;
        for (int p0 = 0; p0 < N_PTS; p0 += 64) {
            const int p = p0 + lane;
            const float q0 = T0[p], q1 = T1[p], q2 = T2[p], q3 = T3[p];
            const float q4 = T4[p], q5 = T5[p], q6 = T6[p];
            float dot = c0 * q0;
            dot = dot + c1 * q1;
            dot = dot + c2a * q2;
            dot = dot + c3 * q3;
            dot = dot + c4 * q4;
            dot = dot + c5 * q5;
            dot = dot + c6 * q6;
            const float xx = XB[p];
            const float d2 = (csq + xx) - 2.0f * dot;
            topk_insert(d2, p, lane, ld, li, kd, ki);
        }
    } else {
        for (int p0 = 0; p0 < N_PTS; p0 += 64) {
            const int p = p0 + lane;
            const float* q = X + (size_t)p * ATTR;
            float dot = c0 * q[0];
            dot = dot + c1 * q[1];
            dot = dot + c2a * q[2];
            dot = dot + c3 * q[3];
            dot = dot + c4 * q[4];
            dot = dot + c5 * q[5];
            dot = dot + c6 * q[6];
            float xx = q[0] * q[0];
            xx = xx + q[1] * q[1];
            xx = xx + q[2] * q[2];
            xx = xx + q[3] * q[3];
            xx = xx + q[4] * q[4];
            xx = xx + q[5] * q[5];
            xx = xx + q[6] * q[6];
            const float d2 = (csq + xx) - 2.0f * dot;
            topk_insert(d2, p, lane, ld, li, kd, ki);
        }
    }

    // neighborhood output: lane j writes rank-j neighbor (ascending (d2,idx))
    if (lane < KNN_K) {
        const float* q = X + (size_t)li * ATTR;
        float* o = out + OFF_NB + ((size_t)gg * KNN_K + lane) * ATTR;
        o[0] = q[0] - c0;
        o[1] = q[1] - c1;
        o[2] = q[2] - c2a;
        o[3] = q[3];
        o[4] = q[4];
        o[5] = q[5];
        o[6] = q[6];
    }
}

extern "C" void kernel_launch(void* const* d_in, const int* in_sizes, int n_in,
                              void* d_out, int out_size, void* d_ws, size_t ws_size,
                              hipStream_t stream) {
    const float* xyz = (const float*)d_in[0];
    float* out = (float*)d_out;

    const size_t need = (size_t)(B_SZ * N_PTS) * (1 + ATTR) * sizeof(float);  // 4 MiB
    const bool use_ws = ws_size >= need;
    float* x2 = use_ws ? (float*)d_ws : nullptr;
    float* xt = use_ws ? ((float*)d_ws + B_SZ * N_PTS) : nullptr;

    if (use_ws) {
        prep_kernel<<<(B_SZ * N_PTS + 255) / 256, 256, 0, stream>>>(xyz, x2, xt);
    }
    fps_kernel<<<B_SZ, 1024, 0, stream>>>(xyz, out);
    knn_kernel<<<(B_SZ * NGROUP) / 4, 256, 0, stream>>>(xyz, x2, xt, out);
}